// Round 2
// baseline (384.909 us; speedup 1.0000x reference)
//
#include <hip/hip_runtime.h>
#include <hip/hip_bf16.h>
#include <math.h>

// Modulated SIREN over 2-bit coordinate fields. The grading reference is a
// float32 re-execution of the jax graph, and the network is chaotic
// (per-layer error gain ~21-30x, sin args ~N(0,900^2)), so we must replicate
// the f32 rounding chain op-by-op at the early layers:
//   - all dots: sequential ascending-k fma from acc=0 (canonical BLAS order)
//   - p = fl(30*m); x = fl(t + p); arg = fl(30*x); h = sinf(arg)
//   - fbar() value barriers stop hipcc's -ffp-contract=fast from re-fusing
// Memoization: hidden state after layer L depends only on the leading 2-bit
// fields -> tables of 256 / 4096 / 65536 rows instead of 262144 GEMVs.
//
// c1 = x89*64 + y89*16 + (y67*4+x67);  c2 = c1*16 + (y45*4+x45);
// c3 = c2*16 + (y23*4+x23);  i3 = y01*4+x01

__device__ __forceinline__ float fbar(float v) {
  asm volatile("" : "+v"(v));
  return v;
}

// M[j][i][d] = emb[j][i] @ modW[j]  (f32, sequential fma)
__global__ void k_mod(const float* __restrict__ emb, const float* __restrict__ modW,
                      float* __restrict__ Mf) {
  int ji = blockIdx.x;  // j*16 + i
  int j = ji >> 4, i = ji & 15, d = threadIdx.x;
  float acc = 0.0f;
#pragma unroll
  for (int e = 0; e < 16; ++e)
    acc = __builtin_fmaf(emb[j * 256 + i * 16 + e], modW[(j * 16 + e) * 256 + d], acc);
  Mf[ji * 256 + d] = acc;
}

// H1[c1][d] = sinf(30*( (lvx*W0[0]+lvy*W0[1]) + b0 + 30*M0[i0] ))  exact f32 chain
__global__ void k_h1(const float* __restrict__ W0, const float* __restrict__ b0,
                     const float* __restrict__ Mf0, float* __restrict__ H1) {
  int c1 = blockIdx.x, d = threadIdx.x;
  float lvx = (float)((c1 >> 6) & 3), lvy = (float)((c1 >> 4) & 3);
  int i0 = c1 & 15;
  float t = fbar(lvx * W0[d]);
  t = __builtin_fmaf(lvy, W0[256 + d], t);
  t = fbar(t + b0[d]);
  float p = fbar(30.0f * Mf0[i0 * 256 + d]);
  float x = fbar(t + p);
  H1[c1 * 256 + d] = sinf(fbar(30.0f * x));
}

// H2[c1*16+i1][d] from H1[c1] @ Wh0 : K=256 sequential fma, then 16 modulator variants
__global__ void k_h2(const float* __restrict__ H1, const float* __restrict__ Wh0,
                     const float* __restrict__ bh0, const float* __restrict__ Mf1,
                     float* __restrict__ H2) {
  __shared__ float xs[256];
  int c1 = blockIdx.x, d = threadIdx.x;
  xs[d] = H1[c1 * 256 + d];
  __syncthreads();
  float acc = 0.0f;
  for (int k = 0; k < 256; ++k)
    acc = __builtin_fmaf(xs[k], Wh0[k * 256 + d], acc);
  float t = fbar(acc + bh0[d]);
#pragma unroll 1
  for (int i1 = 0; i1 < 16; ++i1) {
    float p = fbar(30.0f * Mf1[i1 * 256 + d]);
    float x = fbar(t + p);
    H2[(c1 * 16 + i1) * 256 + d] = sinf(fbar(30.0f * x));
  }
}

// H3[c2*16+i2][d] from H2[c2] @ Wh1 : 16 c2 rows per block (Wh1 amortized),
// per-(row,d) chain still sequential ascending k.
__global__ void k_h3(const float* __restrict__ H2, const float* __restrict__ W1,
                     const float* __restrict__ b1, const float* __restrict__ Mf2,
                     float* __restrict__ H3) {
  __shared__ float xs[16][256];
  int b = blockIdx.x, d = threadIdx.x;
#pragma unroll
  for (int r = 0; r < 16; ++r) xs[r][d] = H2[(b * 16 + r) * 256 + d];
  __syncthreads();
  float m2[16];
#pragma unroll
  for (int i = 0; i < 16; ++i) m2[i] = fbar(30.0f * Mf2[i * 256 + d]);
  float acc[16];
#pragma unroll
  for (int r = 0; r < 16; ++r) acc[r] = 0.0f;
  for (int k = 0; k < 256; ++k) {
    float w = W1[k * 256 + d];
#pragma unroll
    for (int r = 0; r < 16; ++r) acc[r] = __builtin_fmaf(xs[r][k], w, acc[r]);
  }
  float bias = b1[d];
#pragma unroll 1
  for (int r = 0; r < 16; ++r) {
    float t = fbar(acc[r] + bias);
    int c3base = (b * 16 + r) * 16;
#pragma unroll 1
    for (int i = 0; i < 16; ++i) {
      float x = fbar(t + m2[i]);
      H3[(size_t)(c3base + i) * 256 + d] = sinf(fbar(30.0f * x));
    }
  }
}

// G3 = H3 @ Wh2 + bh2  [65536,256]x[256,256] f32 GEMM (tolerance here is loose)
__global__ void __launch_bounds__(256) k_gemmd(const float* __restrict__ H3,
                                               const float* __restrict__ W2,
                                               const float* __restrict__ b2,
                                               float* __restrict__ G3) {
  __shared__ __align__(16) float As[64 * 256];  // 64 KiB
  int t = threadIdx.x;
  size_t r0 = (size_t)blockIdx.x * 64;
  const float4* src = (const float4*)(H3 + r0 * 256);
  float4* dst = (float4*)As;
#pragma unroll
  for (int i = 0; i < 16; ++i) dst[t + i * 256] = src[t + i * 256];
  __syncthreads();
  float acc[64];
#pragma unroll
  for (int r = 0; r < 64; ++r) acc[r] = 0.0f;
  float w0 = W2[0 * 256 + t];
  float w1 = W2[1 * 256 + t];
  float w2 = W2[2 * 256 + t];
  float w3 = W2[3 * 256 + t];
#pragma unroll 1
  for (int k0 = 0; k0 < 256; k0 += 4) {
    float nw0 = 0.f, nw1 = 0.f, nw2 = 0.f, nw3 = 0.f;
    if (k0 < 252) {
      nw0 = W2[(k0 + 4) * 256 + t];
      nw1 = W2[(k0 + 5) * 256 + t];
      nw2 = W2[(k0 + 6) * 256 + t];
      nw3 = W2[(k0 + 7) * 256 + t];
    }
#pragma unroll
    for (int r = 0; r < 64; ++r) {
      float4 a = *(const float4*)(As + r * 256 + k0);
      acc[r] = __builtin_fmaf(a.x, w0, acc[r]);
      acc[r] = __builtin_fmaf(a.y, w1, acc[r]);
      acc[r] = __builtin_fmaf(a.z, w2, acc[r]);
      acc[r] = __builtin_fmaf(a.w, w3, acc[r]);
    }
    w0 = nw0; w1 = nw1; w2 = nw2; w3 = nw3;
  }
  float bias = b2[t];
#pragma unroll
  for (int r = 0; r < 64; ++r)
    G3[(r0 + r) * 256 + t] = acc[r] + bias;
}

// Per point: out = sinf(30*(G3[c3] + 30*M3[i3])) @ Wl + bl.  Wave per point.
__global__ void k_out(const int* __restrict__ coords, const float* __restrict__ G3,
                      const float* __restrict__ Mf3, const float* __restrict__ Wl,
                      const float* __restrict__ bl, float* __restrict__ out,
                      int N, int nwaves) {
  int gtid = blockIdx.x * blockDim.x + threadIdx.x;
  int wid = gtid >> 6, lane = gtid & 63;
  float wl0[4], wl1[4], wl2[4];
#pragma unroll
  for (int j = 0; j < 4; ++j) {
    wl0[j] = Wl[(lane * 4 + j) * 3 + 0];
    wl1[j] = Wl[(lane * 4 + j) * 3 + 1];
    wl2[j] = Wl[(lane * 4 + j) * 3 + 2];
  }
  float blv0 = bl[0], blv1 = bl[1], blv2 = bl[2];
  for (int n = wid; n < N; n += nwaves) {
    int x = coords[2 * n], y = coords[2 * n + 1];
    int c1 = ((x >> 8) & 3) * 64 + ((y >> 8) & 3) * 16 +
             (((y >> 6) & 3) * 4 + ((x >> 6) & 3));
    int i1 = ((y >> 4) & 3) * 4 + ((x >> 4) & 3);
    int i2 = ((y >> 2) & 3) * 4 + ((x >> 2) & 3);
    int i3 = (y & 3) * 4 + (x & 3);
    int c3 = (c1 * 16 + i1) * 16 + i2;
    float4 g = *(const float4*)(G3 + (size_t)c3 * 256 + lane * 4);
    float4 m = *(const float4*)(Mf3 + i3 * 256 + lane * 4);
    float h[4];
    {
      float p, xv;
      p = fbar(30.0f * m.x); xv = fbar(g.x + p); h[0] = sinf(fbar(30.0f * xv));
      p = fbar(30.0f * m.y); xv = fbar(g.y + p); h[1] = sinf(fbar(30.0f * xv));
      p = fbar(30.0f * m.z); xv = fbar(g.z + p); h[2] = sinf(fbar(30.0f * xv));
      p = fbar(30.0f * m.w); xv = fbar(g.w + p); h[3] = sinf(fbar(30.0f * xv));
    }
    float p0 = 0.f, p1 = 0.f, p2 = 0.f;
#pragma unroll
    for (int j = 0; j < 4; ++j) {
      p0 = __builtin_fmaf(h[j], wl0[j], p0);
      p1 = __builtin_fmaf(h[j], wl1[j], p1);
      p2 = __builtin_fmaf(h[j], wl2[j], p2);
    }
#pragma unroll
    for (int off = 32; off > 0; off >>= 1) {
      p0 += __shfl_xor(p0, off);
      p1 += __shfl_xor(p1, off);
      p2 += __shfl_xor(p2, off);
    }
    if (lane == 0) {
      out[n * 3 + 0] = p0 + blv0;
      out[n * 3 + 1] = p1 + blv1;
      out[n * 3 + 2] = p2 + blv2;
    }
  }
}

// -------- fallback (ws too small): exact-f32 direct, block per point --------
__global__ void k_direct(const int* __restrict__ coords, const float* __restrict__ W0,
                         const float* __restrict__ b0, const float* __restrict__ Wh,
                         const float* __restrict__ bh, const float* __restrict__ emb,
                         const float* __restrict__ modW, const float* __restrict__ Wl,
                         const float* __restrict__ bl, float* __restrict__ out) {
  __shared__ float xs[256];
  __shared__ float red[256];
  int n = blockIdx.x, d = threadIdx.x;
  int x = coords[2 * n], y = coords[2 * n + 1];
  float lvx = (float)((x >> 8) & 3), lvy = (float)((y >> 8) & 3);
  int idx[4];
  idx[0] = ((y >> 6) & 3) * 4 + ((x >> 6) & 3);
  idx[1] = ((y >> 4) & 3) * 4 + ((x >> 4) & 3);
  idx[2] = ((y >> 2) & 3) * 4 + ((x >> 2) & 3);
  idx[3] = (y & 3) * 4 + (x & 3);
  float m = 0.0f;
#pragma unroll
  for (int e = 0; e < 16; ++e)
    m = __builtin_fmaf(emb[idx[0] * 16 + e], modW[e * 256 + d], m);
  float t = fbar(lvx * W0[d]);
  t = __builtin_fmaf(lvy, W0[256 + d], t);
  t = fbar(t + b0[d]);
  float p = fbar(30.0f * m);
  float xv = fbar(t + p);
  xs[d] = sinf(fbar(30.0f * xv));
  __syncthreads();
  for (int j = 0; j < 3; ++j) {
    float acc = 0.0f;
    for (int k = 0; k < 256; ++k)
      acc = __builtin_fmaf(xs[k], Wh[j * 65536 + k * 256 + d], acc);
    float tt = fbar(acc + bh[j * 256 + d]);
    m = 0.0f;
#pragma unroll
    for (int e = 0; e < 16; ++e)
      m = __builtin_fmaf(emb[(j + 1) * 256 + idx[j + 1] * 16 + e],
                         modW[((j + 1) * 16 + e) * 256 + d], m);
    p = fbar(30.0f * m);
    xv = fbar(tt + p);
    float h = sinf(fbar(30.0f * xv));
    __syncthreads();
    xs[d] = h;
    __syncthreads();
  }
  for (int q = 0; q < 3; ++q) {
    red[d] = xs[d] * Wl[d * 3 + q];
    __syncthreads();
    for (int s = 128; s > 0; s >>= 1) {
      if (d < s) red[d] += red[d + s];
      __syncthreads();
    }
    if (d == 0) out[n * 3 + q] = red[0] + bl[q];
    __syncthreads();
  }
}

// -------------------- launch --------------------
extern "C" void kernel_launch(void* const* d_in, const int* in_sizes, int n_in,
                              void* d_out, int out_size, void* d_ws, size_t ws_size,
                              hipStream_t stream) {
  const int*   coords = (const int*)d_in[0];
  const float* W0   = (const float*)d_in[1];
  const float* b0   = (const float*)d_in[2];
  const float* Wh   = (const float*)d_in[3];
  const float* bh   = (const float*)d_in[4];
  const float* emb  = (const float*)d_in[5];
  const float* modW = (const float*)d_in[6];
  const float* Wl   = (const float*)d_in[7];
  const float* bl   = (const float*)d_in[8];
  float* out = (float*)d_out;
  const int N = in_sizes[0] / 2;

  const size_t OFF_MF = 0;          // 4*16*256*4   = 65536
  const size_t OFF_H1 = 65536;      // 256*256*4    = 262144
  const size_t OFF_H2 = 327680;     // 4096*256*4   = 4194304
  const size_t OFF_H3 = 4521984;    // 65536*256*4  = 67108864
  const size_t OFF_G3 = 71630848;   // 65536*256*4  = 67108864
  const size_t NEED   = 138739712;  // ~132.3 MB

  if (ws_size >= NEED) {
    char* ws = (char*)d_ws;
    float* Mf = (float*)(ws + OFF_MF);
    float* H1 = (float*)(ws + OFF_H1);
    float* H2 = (float*)(ws + OFF_H2);
    float* H3 = (float*)(ws + OFF_H3);
    float* G3 = (float*)(ws + OFF_G3);

    k_mod<<<64, 256, 0, stream>>>(emb, modW, Mf);
    k_h1<<<256, 256, 0, stream>>>(W0, b0, Mf, H1);
    k_h2<<<256, 256, 0, stream>>>(H1, Wh, bh, Mf + 4096, H2);
    k_h3<<<256, 256, 0, stream>>>(H2, Wh + 65536, bh + 256, Mf + 8192, H3);
    k_gemmd<<<1024, 256, 0, stream>>>(H3, Wh + 131072, bh + 512, G3);
    k_out<<<2048, 256, 0, stream>>>(coords, G3, Mf + 12288, Wl, bl, out, N,
                                    2048 * 256 / 64);
  } else {
    k_direct<<<N, 256, 0, stream>>>(coords, W0, b0, Wh, bh, emb, modW, Wl, bl, out);
  }
}

// Round 3
// 226.697 us; speedup vs baseline: 1.6979x; 1.6979x over previous
//
#include <hip/hip_runtime.h>
#include <hip/hip_bf16.h>
#include <math.h>

// Modulated SIREN over 2-bit coordinate fields. Reference is a float32
// re-execution; network is chaotic (per-layer gain ~21-30x) so layers 1-2
// replicate the f32 rounding chain op-by-op (sequential fma, fbar value
// barriers against -ffp-contract re-fusion). Layers 3+ have loose tolerance.
// Layer-4 GEMM (65536x256 @ 256x256) runs on MFMA via exact bf16 2-term
// split: G3 = Ah*Bh + Ah*Bl + Al*Bh as one K=768 bf16 GEMM with
// B2 = [Bh; Bl; Bh] stacked and A sourced as [Ah, Ah, Al].

typedef float  f32x4  __attribute__((ext_vector_type(4)));
typedef int    i32x4  __attribute__((ext_vector_type(4)));
typedef __bf16 bf16x8 __attribute__((ext_vector_type(8)));

__device__ __forceinline__ float fbar(float v) {
  asm volatile("" : "+v"(v));
  return v;
}

__device__ __forceinline__ unsigned short f2bf_rne(float x) {
  unsigned u = __float_as_uint(x);
  unsigned r = (u + 0x7fffu + ((u >> 16) & 1u)) >> 16;
  return (unsigned short)r;
}

// M[j][i][d] = emb[j][i] @ modW[j]  (f32, sequential fma)
__global__ void k_mod(const float* __restrict__ emb, const float* __restrict__ modW,
                      float* __restrict__ Mf) {
  int ji = blockIdx.x;  // j*16 + i
  int j = ji >> 4, i = ji & 15, d = threadIdx.x;
  float acc = 0.0f;
#pragma unroll
  for (int e = 0; e < 16; ++e)
    acc = __builtin_fmaf(emb[j * 256 + i * 16 + e], modW[(j * 16 + e) * 256 + d], acc);
  Mf[ji * 256 + d] = acc;
}

// H1[c1][d] = sinf(30*( (lvx*W0[0]+lvy*W0[1]) + b0 + 30*M0[i0] ))
__global__ void k_h1(const float* __restrict__ W0, const float* __restrict__ b0,
                     const float* __restrict__ Mf0, float* __restrict__ H1) {
  int c1 = blockIdx.x, d = threadIdx.x;
  float lvx = (float)((c1 >> 6) & 3), lvy = (float)((c1 >> 4) & 3);
  int i0 = c1 & 15;
  float t = fbar(lvx * W0[d]);
  t = __builtin_fmaf(lvy, W0[256 + d], t);
  t = fbar(t + b0[d]);
  float p = fbar(30.0f * Mf0[i0 * 256 + d]);
  float x = fbar(t + p);
  H1[c1 * 256 + d] = sinf(fbar(30.0f * x));
}

// H2[c1*16+i1][d] from H1[c1] @ Wh0 : K=256 sequential fma, 16 modulator variants
__global__ void k_h2(const float* __restrict__ H1, const float* __restrict__ Wh0,
                     const float* __restrict__ bh0, const float* __restrict__ Mf1,
                     float* __restrict__ H2) {
  __shared__ float xs[256];
  int c1 = blockIdx.x, d = threadIdx.x;
  xs[d] = H1[c1 * 256 + d];
  __syncthreads();
  float acc = 0.0f;
  for (int k = 0; k < 256; ++k)
    acc = __builtin_fmaf(xs[k], Wh0[k * 256 + d], acc);
  float t = fbar(acc + bh0[d]);
#pragma unroll 1
  for (int i1 = 0; i1 < 16; ++i1) {
    float p = fbar(30.0f * Mf1[i1 * 256 + d]);
    float x = fbar(t + p);
    H2[(c1 * 16 + i1) * 256 + d] = sinf(fbar(30.0f * x));
  }
}

// H3 rows, emitted directly as exact bf16 split Ah + Al.
__global__ void k_h3ab(const float* __restrict__ H2, const float* __restrict__ W1,
                       const float* __restrict__ b1, const float* __restrict__ Mf2,
                       unsigned short* __restrict__ Ah, unsigned short* __restrict__ Al) {
  __shared__ float xs[16][256];
  int b = blockIdx.x, d = threadIdx.x;
#pragma unroll
  for (int r = 0; r < 16; ++r) xs[r][d] = H2[(b * 16 + r) * 256 + d];
  __syncthreads();
  float m2[16];
#pragma unroll
  for (int i = 0; i < 16; ++i) m2[i] = fbar(30.0f * Mf2[i * 256 + d]);
  float acc[16];
#pragma unroll
  for (int r = 0; r < 16; ++r) acc[r] = 0.0f;
  for (int k = 0; k < 256; ++k) {
    float w = W1[k * 256 + d];
#pragma unroll
    for (int r = 0; r < 16; ++r) acc[r] = __builtin_fmaf(xs[r][k], w, acc[r]);
  }
  float bias = b1[d];
#pragma unroll 1
  for (int r = 0; r < 16; ++r) {
    float t = fbar(acc[r] + bias);
    int c3base = (b * 16 + r) * 16;
#pragma unroll 1
    for (int i = 0; i < 16; ++i) {
      float x = fbar(t + m2[i]);
      float h = sinf(fbar(30.0f * x));
      unsigned short hi = f2bf_rne(h);
      float hif = __uint_as_float((unsigned)hi << 16);
      unsigned short lo = f2bf_rne(h - hif);
      size_t o = (size_t)(c3base + i) * 256 + d;
      Ah[o] = hi;
      Al[o] = lo;
    }
  }
}

// B2T[col][k'] over k'=0..767 : [Bh ; Bl ; Bh] from W2[k][col], N-major (B^T).
__global__ void k_splitb(const float* __restrict__ W2, unsigned short* __restrict__ B2T) {
  int col = blockIdx.x, k = threadIdx.x;
  float w = W2[k * 256 + col];
  unsigned short hi = f2bf_rne(w);
  float hif = __uint_as_float((unsigned)hi << 16);
  unsigned short lo = f2bf_rne(w - hif);
  B2T[col * 768 + k] = hi;
  B2T[col * 768 + 256 + k] = lo;
  B2T[col * 768 + 512 + k] = hi;
}

// G3 = [Ah,Ah,Al] @ [Bh;Bl;Bh] + b2 : bf16 MFMA GEMM, M=65536 N=256 K=768.
// Block: 512 thr (8 waves, 2x4), tile 128x256, K-chunks of 32, 1-deep prefetch.
// LDS rows padded to 40 shorts (80B: 16B-aligned, <=2-way bank aliasing).
__global__ void __launch_bounds__(512, 1) k_gemm(
    const unsigned short* __restrict__ Ah, const unsigned short* __restrict__ Al,
    const unsigned short* __restrict__ B2T, const float* __restrict__ b2,
    float* __restrict__ G3) {
  __shared__ unsigned short As[128 * 40];
  __shared__ unsigned short Bs[256 * 40];
  const int t = threadIdx.x;
  const int lane = t & 63, wid = t >> 6;
  const int l15 = lane & 15, l4 = lane >> 4;
  const int wm = (wid >> 2) * 64;   // 0 / 64
  const int wn = (wid & 3) * 64;    // 0 / 64 / 128 / 192
  const size_t r0 = (size_t)blockIdx.x * 128;

  const int s_arow = t >> 2, s_apart = t & 3;     // A: 128 rows x 4 x16B
  const int s_bcol0 = t >> 2, s_bcol1 = 128 + (t >> 2), s_bpart = t & 3;

  f32x4 acc[4][4];
#pragma unroll
  for (int rf = 0; rf < 4; ++rf)
#pragma unroll
    for (int cf = 0; cf < 4; ++cf) acc[rf][cf] = (f32x4){0.f, 0.f, 0.f, 0.f};

  i32x4 ra, rb0, rb1;
  ra  = *(const i32x4*)(Ah + ((r0 + s_arow) << 8) + s_apart * 8);
  rb0 = *(const i32x4*)(B2T + s_bcol0 * 768 + s_bpart * 8);
  rb1 = *(const i32x4*)(B2T + s_bcol1 * 768 + s_bpart * 8);

#pragma unroll 1
  for (int c = 0; c < 24; ++c) {
    *(i32x4*)(As + s_arow * 40 + s_apart * 8) = ra;
    *(i32x4*)(Bs + s_bcol0 * 40 + s_bpart * 8) = rb0;
    *(i32x4*)(Bs + s_bcol1 * 40 + s_bpart * 8) = rb1;
    __syncthreads();
    if (c < 23) {
      int cn = c + 1;
      int kk = cn & 7;
      const unsigned short* asrc = (cn >= 16) ? Al : Ah;
      ra  = *(const i32x4*)(asrc + ((r0 + s_arow) << 8) + kk * 32 + s_apart * 8);
      rb0 = *(const i32x4*)(B2T + s_bcol0 * 768 + cn * 32 + s_bpart * 8);
      rb1 = *(const i32x4*)(B2T + s_bcol1 * 768 + cn * 32 + s_bpart * 8);
    }
    bf16x8 af[4], bfr[4];
#pragma unroll
    for (int rf = 0; rf < 4; ++rf)
      af[rf] = __builtin_bit_cast(
          bf16x8, *(const i32x4*)(As + (wm + rf * 16 + l15) * 40 + l4 * 8));
#pragma unroll
    for (int cf = 0; cf < 4; ++cf)
      bfr[cf] = __builtin_bit_cast(
          bf16x8, *(const i32x4*)(Bs + (wn + cf * 16 + l15) * 40 + l4 * 8));
#pragma unroll
    for (int rf = 0; rf < 4; ++rf)
#pragma unroll
      for (int cf = 0; cf < 4; ++cf)
        acc[rf][cf] = __builtin_amdgcn_mfma_f32_16x16x32_bf16(
            af[rf], bfr[cf], acc[rf][cf], 0, 0, 0);
    __syncthreads();
  }

#pragma unroll
  for (int cf = 0; cf < 4; ++cf) {
    float bias = b2[wn + cf * 16 + l15];
#pragma unroll
    for (int rf = 0; rf < 4; ++rf) {
      size_t rbase = r0 + wm + rf * 16 + l4 * 4;
#pragma unroll
      for (int j = 0; j < 4; ++j)
        G3[(rbase + j) * 256 + wn + cf * 16 + l15] = acc[rf][cf][j] + bias;
    }
  }
}

// Per point: out = sinf(30*(G3[c3] + 30*M3[i3])) @ Wl + bl.  Wave per point.
__global__ void k_out(const int* __restrict__ coords, const float* __restrict__ G3,
                      const float* __restrict__ Mf3, const float* __restrict__ Wl,
                      const float* __restrict__ bl, float* __restrict__ out,
                      int N, int nwaves) {
  int gtid = blockIdx.x * blockDim.x + threadIdx.x;
  int wid = gtid >> 6, lane = gtid & 63;
  float wl0[4], wl1[4], wl2[4];
#pragma unroll
  for (int j = 0; j < 4; ++j) {
    wl0[j] = Wl[(lane * 4 + j) * 3 + 0];
    wl1[j] = Wl[(lane * 4 + j) * 3 + 1];
    wl2[j] = Wl[(lane * 4 + j) * 3 + 2];
  }
  float blv0 = bl[0], blv1 = bl[1], blv2 = bl[2];
  for (int n = wid; n < N; n += nwaves) {
    int x = coords[2 * n], y = coords[2 * n + 1];
    int c1 = ((x >> 8) & 3) * 64 + ((y >> 8) & 3) * 16 +
             (((y >> 6) & 3) * 4 + ((x >> 6) & 3));
    int i1 = ((y >> 4) & 3) * 4 + ((x >> 4) & 3);
    int i2 = ((y >> 2) & 3) * 4 + ((x >> 2) & 3);
    int i3 = (y & 3) * 4 + (x & 3);
    int c3 = (c1 * 16 + i1) * 16 + i2;
    float4 g = *(const float4*)(G3 + (size_t)c3 * 256 + lane * 4);
    float4 m = *(const float4*)(Mf3 + i3 * 256 + lane * 4);
    float h[4];
    {
      float p, xv;
      p = fbar(30.0f * m.x); xv = fbar(g.x + p); h[0] = sinf(fbar(30.0f * xv));
      p = fbar(30.0f * m.y); xv = fbar(g.y + p); h[1] = sinf(fbar(30.0f * xv));
      p = fbar(30.0f * m.z); xv = fbar(g.z + p); h[2] = sinf(fbar(30.0f * xv));
      p = fbar(30.0f * m.w); xv = fbar(g.w + p); h[3] = sinf(fbar(30.0f * xv));
    }
    float p0 = 0.f, p1 = 0.f, p2 = 0.f;
#pragma unroll
    for (int j = 0; j < 4; ++j) {
      p0 = __builtin_fmaf(h[j], wl0[j], p0);
      p1 = __builtin_fmaf(h[j], wl1[j], p1);
      p2 = __builtin_fmaf(h[j], wl2[j], p2);
    }
#pragma unroll
    for (int off = 32; off > 0; off >>= 1) {
      p0 += __shfl_xor(p0, off);
      p1 += __shfl_xor(p1, off);
      p2 += __shfl_xor(p2, off);
    }
    if (lane == 0) {
      out[n * 3 + 0] = p0 + blv0;
      out[n * 3 + 1] = p1 + blv1;
      out[n * 3 + 2] = p2 + blv2;
    }
  }
}

// -------- fallback (ws too small): exact-f32 direct, block per point --------
__global__ void k_direct(const int* __restrict__ coords, const float* __restrict__ W0,
                         const float* __restrict__ b0, const float* __restrict__ Wh,
                         const float* __restrict__ bh, const float* __restrict__ emb,
                         const float* __restrict__ modW, const float* __restrict__ Wl,
                         const float* __restrict__ bl, float* __restrict__ out) {
  __shared__ float xs[256];
  __shared__ float red[256];
  int n = blockIdx.x, d = threadIdx.x;
  int x = coords[2 * n], y = coords[2 * n + 1];
  float lvx = (float)((x >> 8) & 3), lvy = (float)((y >> 8) & 3);
  int idx[4];
  idx[0] = ((y >> 6) & 3) * 4 + ((x >> 6) & 3);
  idx[1] = ((y >> 4) & 3) * 4 + ((x >> 4) & 3);
  idx[2] = ((y >> 2) & 3) * 4 + ((x >> 2) & 3);
  idx[3] = (y & 3) * 4 + (x & 3);
  float m = 0.0f;
#pragma unroll
  for (int e = 0; e < 16; ++e)
    m = __builtin_fmaf(emb[idx[0] * 16 + e], modW[e * 256 + d], m);
  float t = fbar(lvx * W0[d]);
  t = __builtin_fmaf(lvy, W0[256 + d], t);
  t = fbar(t + b0[d]);
  float p = fbar(30.0f * m);
  float xv = fbar(t + p);
  xs[d] = sinf(fbar(30.0f * xv));
  __syncthreads();
  for (int j = 0; j < 3; ++j) {
    float acc = 0.0f;
    for (int k = 0; k < 256; ++k)
      acc = __builtin_fmaf(xs[k], Wh[j * 65536 + k * 256 + d], acc);
    float tt = fbar(acc + bh[j * 256 + d]);
    m = 0.0f;
#pragma unroll
    for (int e = 0; e < 16; ++e)
      m = __builtin_fmaf(emb[(j + 1) * 256 + idx[j + 1] * 16 + e],
                         modW[((j + 1) * 16 + e) * 256 + d], m);
    p = fbar(30.0f * m);
    xv = fbar(tt + p);
    float h = sinf(fbar(30.0f * xv));
    __syncthreads();
    xs[d] = h;
    __syncthreads();
  }
  for (int q = 0; q < 3; ++q) {
    red[d] = xs[d] * Wl[d * 3 + q];
    __syncthreads();
    for (int s = 128; s > 0; s >>= 1) {
      if (d < s) red[d] += red[d + s];
      __syncthreads();
    }
    if (d == 0) out[n * 3 + q] = red[0] + bl[q];
    __syncthreads();
  }
}

// -------------------- launch --------------------
extern "C" void kernel_launch(void* const* d_in, const int* in_sizes, int n_in,
                              void* d_out, int out_size, void* d_ws, size_t ws_size,
                              hipStream_t stream) {
  const int*   coords = (const int*)d_in[0];
  const float* W0   = (const float*)d_in[1];
  const float* b0   = (const float*)d_in[2];
  const float* Wh   = (const float*)d_in[3];
  const float* bh   = (const float*)d_in[4];
  const float* emb  = (const float*)d_in[5];
  const float* modW = (const float*)d_in[6];
  const float* Wl   = (const float*)d_in[7];
  const float* bl   = (const float*)d_in[8];
  float* out = (float*)d_out;
  const int N = in_sizes[0] / 2;

  // layout: Mf | B2T | Ah | Al | (G3 overlays H1+H2 — H2 dead before k_gemm)
  const size_t OFF_MF  = 0;          //  65536
  const size_t OFF_B2T = 65536;      //  393216
  const size_t OFF_AH  = 458752;     //  33554432
  const size_t OFF_AL  = 34013184;   //  33554432
  const size_t OFF_G3  = 67567616;   //  67108864
  const size_t OFF_H1  = 67567616;   //  262144 (dead before k_gemm)
  const size_t OFF_H2  = 67829760;   //  4194304 (dead before k_gemm)
  const size_t NEED    = 134676480;

  if (ws_size >= NEED) {
    char* ws = (char*)d_ws;
    float*          Mf  = (float*)(ws + OFF_MF);
    unsigned short* B2T = (unsigned short*)(ws + OFF_B2T);
    unsigned short* Ahp = (unsigned short*)(ws + OFF_AH);
    unsigned short* Alp = (unsigned short*)(ws + OFF_AL);
    float*          G3  = (float*)(ws + OFF_G3);
    float*          H1  = (float*)(ws + OFF_H1);
    float*          H2  = (float*)(ws + OFF_H2);

    k_mod<<<64, 256, 0, stream>>>(emb, modW, Mf);
    k_splitb<<<256, 256, 0, stream>>>(Wh + 131072, B2T);
    k_h1<<<256, 256, 0, stream>>>(W0, b0, Mf, H1);
    k_h2<<<256, 256, 0, stream>>>(H1, Wh, bh, Mf + 4096, H2);
    k_h3ab<<<256, 256, 0, stream>>>(H2, Wh + 65536, bh + 256, Mf + 8192, Ahp, Alp);
    k_gemm<<<512, 512, 0, stream>>>(Ahp, Alp, B2T, bh + 512, G3);
    k_out<<<2048, 256, 0, stream>>>(coords, G3, Mf + 12288, Wl, bl, out, N,
                                    2048 * 256 / 64);
  } else {
    k_direct<<<N, 256, 0, stream>>>(coords, W0, b0, Wh, bh, emb, modW, Wl, bl, out);
  }
}

// Round 4
// 190.101 us; speedup vs baseline: 2.0248x; 1.1925x over previous
//
#include <hip/hip_runtime.h>
#include <hip/hip_bf16.h>
#include <math.h>

// Modulated SIREN over 2-bit coordinate fields. Reference is a float32
// re-execution; network is chaotic (per-layer gain ~21-30x) so layers 1-2
// replicate the f32 rounding chain op-by-op (sequential fma, fbar value
// barriers against -ffp-contract re-fusion) with libm sinf. Layers 3-4
// tolerate ~1e-4 sin error (amplification <=25x, margin 0.034) -> 18-op
// inline sin30 (double-single range reduction + deg-11 odd Taylor).
// Layer-4 GEMM (65536x256 @ 256x256) runs on MFMA via exact bf16 2-term
// split: G3 = Ah*Bh + Ah*Bl + Al*Bh as one K=768 bf16 GEMM.

typedef float  f32x4  __attribute__((ext_vector_type(4)));
typedef int    i32x4  __attribute__((ext_vector_type(4)));
typedef __bf16 bf16x8 __attribute__((ext_vector_type(8)));

__device__ __forceinline__ float fbar(float v) {
  asm volatile("" : "+v"(v));
  return v;
}

__device__ __forceinline__ unsigned short f2bf_rne(float x) {
  unsigned u = __float_as_uint(x);
  unsigned r = (u + 0x7fffu + ((u >> 16) & 1u)) >> 16;
  return (unsigned short)r;
}

// sin(30*x), |x| <~ 200. Phase: rev = x*(30/2pi) in double-single (exact
// fma residue), fold by half-periods via rint, deg-11 odd Taylor for
// sin(2*pi*g) on g in [-0.25,0.25], parity sign by bit-xor. Abs err ~6e-7.
__device__ __forceinline__ float sin30(float x) {
  const float Ch = 4.774648189544678f;   // hi(30/(2pi))
  const float Cl = 1.0321218e-07f;       // 30/(2pi) - Ch
  float revh = x * Ch;
  fbar(revh);
  float e    = __builtin_fmaf(x, Ch, -revh);   // exact product residue
  float revl = __builtin_fmaf(x, Cl, e);
  float k2   = __builtin_rintf(revh + revh);   // nearest half-period count
  float g    = __builtin_fmaf(k2, -0.5f, revh) + revl;  // exact fold + lo
  float g2 = g * g;
  float r = -15.0946f;
  r = __builtin_fmaf(r, g2, 42.0601f);
  r = __builtin_fmaf(r, g2, -76.70585f);
  r = __builtin_fmaf(r, g2, 81.6052492f);
  r = __builtin_fmaf(r, g2, -41.341702f);
  r = __builtin_fmaf(r, g2, 6.2831853f);
  float s = g * r;
  int ki = (int)k2;
  return __uint_as_float(__float_as_uint(s) ^ ((unsigned)(ki & 1) << 31));
}

// M[j][i][d] = emb[j][i] @ modW[j]  (f32, sequential fma)
__global__ void k_mod(const float* __restrict__ emb, const float* __restrict__ modW,
                      float* __restrict__ Mf) {
  int ji = blockIdx.x;  // j*16 + i
  int j = ji >> 4, i = ji & 15, d = threadIdx.x;
  float acc = 0.0f;
#pragma unroll
  for (int e = 0; e < 16; ++e)
    acc = __builtin_fmaf(emb[j * 256 + i * 16 + e], modW[(j * 16 + e) * 256 + d], acc);
  Mf[ji * 256 + d] = acc;
}

// H1[c1][d] = sinf(30*( (lvx*W0[0]+lvy*W0[1]) + b0 + 30*M0[i0] ))  (libm)
__global__ void k_h1(const float* __restrict__ W0, const float* __restrict__ b0,
                     const float* __restrict__ Mf0, float* __restrict__ H1) {
  int c1 = blockIdx.x, d = threadIdx.x;
  float lvx = (float)((c1 >> 6) & 3), lvy = (float)((c1 >> 4) & 3);
  int i0 = c1 & 15;
  float t = fbar(lvx * W0[d]);
  t = __builtin_fmaf(lvy, W0[256 + d], t);
  t = fbar(t + b0[d]);
  float p = fbar(30.0f * Mf0[i0 * 256 + d]);
  float x = fbar(t + p);
  H1[c1 * 256 + d] = sinf(fbar(30.0f * x));
}

// H2[c1*16+i1][d] from H1[c1] @ Wh0 : K=256 sequential fma (libm sinf)
__global__ void k_h2(const float* __restrict__ H1, const float* __restrict__ Wh0,
                     const float* __restrict__ bh0, const float* __restrict__ Mf1,
                     float* __restrict__ H2) {
  __shared__ float xs[256];
  int c1 = blockIdx.x, d = threadIdx.x;
  xs[d] = H1[c1 * 256 + d];
  __syncthreads();
  float acc = 0.0f;
  for (int k = 0; k < 256; ++k)
    acc = __builtin_fmaf(xs[k], Wh0[k * 256 + d], acc);
  float t = fbar(acc + bh0[d]);
#pragma unroll 1
  for (int i1 = 0; i1 < 16; ++i1) {
    float p = fbar(30.0f * Mf1[i1 * 256 + d]);
    float x = fbar(t + p);
    H2[(c1 * 16 + i1) * 256 + d] = sinf(fbar(30.0f * x));
  }
}

// H3 rows as exact bf16 split Ah+Al. 1024 blocks x 4 c2-rows (occupancy fix).
__global__ void k_h3ab(const float* __restrict__ H2, const float* __restrict__ W1,
                       const float* __restrict__ b1, const float* __restrict__ Mf2,
                       unsigned short* __restrict__ Ah, unsigned short* __restrict__ Al) {
  __shared__ float xs[4][256];
  int b = blockIdx.x, d = threadIdx.x;
#pragma unroll
  for (int r = 0; r < 4; ++r) xs[r][d] = H2[(b * 4 + r) * 256 + d];
  __syncthreads();
  float m2[16];
#pragma unroll
  for (int i = 0; i < 16; ++i) m2[i] = fbar(30.0f * Mf2[i * 256 + d]);
  float acc[4];
#pragma unroll
  for (int r = 0; r < 4; ++r) acc[r] = 0.0f;
  for (int k = 0; k < 256; ++k) {
    float w = W1[k * 256 + d];
#pragma unroll
    for (int r = 0; r < 4; ++r) acc[r] = __builtin_fmaf(xs[r][k], w, acc[r]);
  }
  float bias = b1[d];
#pragma unroll
  for (int r = 0; r < 4; ++r) {
    float t = fbar(acc[r] + bias);
    int c3base = (b * 4 + r) * 16;
#pragma unroll
    for (int i = 0; i < 16; ++i) {
      float x = fbar(t + m2[i]);
      float h = sin30(x);
      unsigned short hi = f2bf_rne(h);
      float hif = __uint_as_float((unsigned)hi << 16);
      unsigned short lo = f2bf_rne(h - hif);
      size_t o = (size_t)(c3base + i) * 256 + d;
      Ah[o] = hi;
      Al[o] = lo;
    }
  }
}

// B2T[col][k'] over k'=0..767 : [Bh ; Bl ; Bh] from W2[k][col], N-major (B^T).
__global__ void k_splitb(const float* __restrict__ W2, unsigned short* __restrict__ B2T) {
  int col = blockIdx.x, k = threadIdx.x;
  float w = W2[k * 256 + col];
  unsigned short hi = f2bf_rne(w);
  float hif = __uint_as_float((unsigned)hi << 16);
  unsigned short lo = f2bf_rne(w - hif);
  B2T[col * 768 + k] = hi;
  B2T[col * 768 + 256 + k] = lo;
  B2T[col * 768 + 512 + k] = hi;
}

// G3 = [Ah,Ah,Al] @ [Bh;Bl;Bh] + b2 : bf16 MFMA GEMM, M=65536 N=256 K=768.
__global__ void __launch_bounds__(512, 1) k_gemm(
    const unsigned short* __restrict__ Ah, const unsigned short* __restrict__ Al,
    const unsigned short* __restrict__ B2T, const float* __restrict__ b2,
    float* __restrict__ G3) {
  __shared__ unsigned short As[128 * 40];
  __shared__ unsigned short Bs[256 * 40];
  const int t = threadIdx.x;
  const int lane = t & 63, wid = t >> 6;
  const int l15 = lane & 15, l4 = lane >> 4;
  const int wm = (wid >> 2) * 64;
  const int wn = (wid & 3) * 64;
  const size_t r0 = (size_t)blockIdx.x * 128;

  const int s_arow = t >> 2, s_apart = t & 3;
  const int s_bcol0 = t >> 2, s_bcol1 = 128 + (t >> 2), s_bpart = t & 3;

  f32x4 acc[4][4];
#pragma unroll
  for (int rf = 0; rf < 4; ++rf)
#pragma unroll
    for (int cf = 0; cf < 4; ++cf) acc[rf][cf] = (f32x4){0.f, 0.f, 0.f, 0.f};

  i32x4 ra, rb0, rb1;
  ra  = *(const i32x4*)(Ah + ((r0 + s_arow) << 8) + s_apart * 8);
  rb0 = *(const i32x4*)(B2T + s_bcol0 * 768 + s_bpart * 8);
  rb1 = *(const i32x4*)(B2T + s_bcol1 * 768 + s_bpart * 8);

#pragma unroll 1
  for (int c = 0; c < 24; ++c) {
    *(i32x4*)(As + s_arow * 40 + s_apart * 8) = ra;
    *(i32x4*)(Bs + s_bcol0 * 40 + s_bpart * 8) = rb0;
    *(i32x4*)(Bs + s_bcol1 * 40 + s_bpart * 8) = rb1;
    __syncthreads();
    if (c < 23) {
      int cn = c + 1;
      int kk = cn & 7;
      const unsigned short* asrc = (cn >= 16) ? Al : Ah;
      ra  = *(const i32x4*)(asrc + ((r0 + s_arow) << 8) + kk * 32 + s_apart * 8);
      rb0 = *(const i32x4*)(B2T + s_bcol0 * 768 + cn * 32 + s_bpart * 8);
      rb1 = *(const i32x4*)(B2T + s_bcol1 * 768 + cn * 32 + s_bpart * 8);
    }
    bf16x8 af[4], bfr[4];
#pragma unroll
    for (int rf = 0; rf < 4; ++rf)
      af[rf] = __builtin_bit_cast(
          bf16x8, *(const i32x4*)(As + (wm + rf * 16 + l15) * 40 + l4 * 8));
#pragma unroll
    for (int cf = 0; cf < 4; ++cf)
      bfr[cf] = __builtin_bit_cast(
          bf16x8, *(const i32x4*)(Bs + (wn + cf * 16 + l15) * 40 + l4 * 8));
#pragma unroll
    for (int rf = 0; rf < 4; ++rf)
#pragma unroll
      for (int cf = 0; cf < 4; ++cf)
        acc[rf][cf] = __builtin_amdgcn_mfma_f32_16x16x32_bf16(
            af[rf], bfr[cf], acc[rf][cf], 0, 0, 0);
    __syncthreads();
  }

#pragma unroll
  for (int cf = 0; cf < 4; ++cf) {
    float bias = b2[wn + cf * 16 + l15];
#pragma unroll
    for (int rf = 0; rf < 4; ++rf) {
      size_t rbase = r0 + wm + rf * 16 + l4 * 4;
#pragma unroll
      for (int j = 0; j < 4; ++j)
        G3[(rbase + j) * 256 + wn + cf * 16 + l15] = acc[rf][cf][j] + bias;
    }
  }
}

// Per point: out = sin30(G3[c3] + 30*M3[i3]) @ Wl + bl.
// 16-lane group per point (4 points/wave): lane l covers d = j*64 + l*4 + k.
__global__ void k_out(const int* __restrict__ coords, const float* __restrict__ G3,
                      const float* __restrict__ Mf3, const float* __restrict__ Wl,
                      const float* __restrict__ bl, float* __restrict__ out,
                      int N, int ngroups) {
  int gtid = blockIdx.x * blockDim.x + threadIdx.x;
  int grp = gtid >> 4, l = gtid & 15;
  float wl[4][4][3];
#pragma unroll
  for (int j = 0; j < 4; ++j)
#pragma unroll
    for (int k = 0; k < 4; ++k) {
      int d = j * 64 + l * 4 + k;
      wl[j][k][0] = Wl[d * 3 + 0];
      wl[j][k][1] = Wl[d * 3 + 1];
      wl[j][k][2] = Wl[d * 3 + 2];
    }
  float blv0 = bl[0], blv1 = bl[1], blv2 = bl[2];
  for (int n = grp; n < N; n += ngroups) {
    int x = coords[2 * n], y = coords[2 * n + 1];
    int c1 = ((x >> 8) & 3) * 64 + ((y >> 8) & 3) * 16 +
             (((y >> 6) & 3) * 4 + ((x >> 6) & 3));
    int i1 = ((y >> 4) & 3) * 4 + ((x >> 4) & 3);
    int i2 = ((y >> 2) & 3) * 4 + ((x >> 2) & 3);
    int i3 = (y & 3) * 4 + (x & 3);
    int c3 = (c1 * 16 + i1) * 16 + i2;
    const float* gp = G3 + (size_t)c3 * 256 + l * 4;
    const float* mp = Mf3 + i3 * 256 + l * 4;
    float p0 = 0.f, p1 = 0.f, p2 = 0.f;
#pragma unroll
    for (int j = 0; j < 4; ++j) {
      float4 g = *(const float4*)(gp + j * 64);
      float4 m = *(const float4*)(mp + j * 64);
      float gv[4] = {g.x, g.y, g.z, g.w};
      float mv[4] = {m.x, m.y, m.z, m.w};
#pragma unroll
      for (int k = 0; k < 4; ++k) {
        float p = fbar(30.0f * mv[k]);
        float xv = fbar(gv[k] + p);
        float h = sin30(xv);
        p0 = __builtin_fmaf(h, wl[j][k][0], p0);
        p1 = __builtin_fmaf(h, wl[j][k][1], p1);
        p2 = __builtin_fmaf(h, wl[j][k][2], p2);
      }
    }
#pragma unroll
    for (int off = 1; off < 16; off <<= 1) {
      p0 += __shfl_xor(p0, off);
      p1 += __shfl_xor(p1, off);
      p2 += __shfl_xor(p2, off);
    }
    if (l == 0) {
      out[n * 3 + 0] = p0 + blv0;
      out[n * 3 + 1] = p1 + blv1;
      out[n * 3 + 2] = p2 + blv2;
    }
  }
}

// -------- fallback (ws too small): exact-f32 direct, block per point --------
__global__ void k_direct(const int* __restrict__ coords, const float* __restrict__ W0,
                         const float* __restrict__ b0, const float* __restrict__ Wh,
                         const float* __restrict__ bh, const float* __restrict__ emb,
                         const float* __restrict__ modW, const float* __restrict__ Wl,
                         const float* __restrict__ bl, float* __restrict__ out) {
  __shared__ float xs[256];
  __shared__ float red[256];
  int n = blockIdx.x, d = threadIdx.x;
  int x = coords[2 * n], y = coords[2 * n + 1];
  float lvx = (float)((x >> 8) & 3), lvy = (float)((y >> 8) & 3);
  int idx[4];
  idx[0] = ((y >> 6) & 3) * 4 + ((x >> 6) & 3);
  idx[1] = ((y >> 4) & 3) * 4 + ((x >> 4) & 3);
  idx[2] = ((y >> 2) & 3) * 4 + ((x >> 2) & 3);
  idx[3] = (y & 3) * 4 + (x & 3);
  float m = 0.0f;
#pragma unroll
  for (int e = 0; e < 16; ++e)
    m = __builtin_fmaf(emb[idx[0] * 16 + e], modW[e * 256 + d], m);
  float t = fbar(lvx * W0[d]);
  t = __builtin_fmaf(lvy, W0[256 + d], t);
  t = fbar(t + b0[d]);
  float p = fbar(30.0f * m);
  float xv = fbar(t + p);
  xs[d] = sinf(fbar(30.0f * xv));
  __syncthreads();
  for (int j = 0; j < 3; ++j) {
    float acc = 0.0f;
    for (int k = 0; k < 256; ++k)
      acc = __builtin_fmaf(xs[k], Wh[j * 65536 + k * 256 + d], acc);
    float tt = fbar(acc + bh[j * 256 + d]);
    m = 0.0f;
#pragma unroll
    for (int e = 0; e < 16; ++e)
      m = __builtin_fmaf(emb[(j + 1) * 256 + idx[j + 1] * 16 + e],
                         modW[((j + 1) * 16 + e) * 256 + d], m);
    p = fbar(30.0f * m);
    xv = fbar(tt + p);
    float h = sinf(fbar(30.0f * xv));
    __syncthreads();
    xs[d] = h;
    __syncthreads();
  }
  for (int q = 0; q < 3; ++q) {
    red[d] = xs[d] * Wl[d * 3 + q];
    __syncthreads();
    for (int s = 128; s > 0; s >>= 1) {
      if (d < s) red[d] += red[d + s];
      __syncthreads();
    }
    if (d == 0) out[n * 3 + q] = red[0] + bl[q];
    __syncthreads();
  }
}

// -------------------- launch --------------------
extern "C" void kernel_launch(void* const* d_in, const int* in_sizes, int n_in,
                              void* d_out, int out_size, void* d_ws, size_t ws_size,
                              hipStream_t stream) {
  const int*   coords = (const int*)d_in[0];
  const float* W0   = (const float*)d_in[1];
  const float* b0   = (const float*)d_in[2];
  const float* Wh   = (const float*)d_in[3];
  const float* bh   = (const float*)d_in[4];
  const float* emb  = (const float*)d_in[5];
  const float* modW = (const float*)d_in[6];
  const float* Wl   = (const float*)d_in[7];
  const float* bl   = (const float*)d_in[8];
  float* out = (float*)d_out;
  const int N = in_sizes[0] / 2;

  // layout: Mf | B2T | Ah | Al | (G3 overlays H1+H2 — dead before k_gemm)
  const size_t OFF_MF  = 0;          //  65536
  const size_t OFF_B2T = 65536;      //  393216
  const size_t OFF_AH  = 458752;     //  33554432
  const size_t OFF_AL  = 34013184;   //  33554432
  const size_t OFF_G3  = 67567616;   //  67108864
  const size_t OFF_H1  = 67567616;   //  262144
  const size_t OFF_H2  = 67829760;   //  4194304
  const size_t NEED    = 134676480;

  if (ws_size >= NEED) {
    char* ws = (char*)d_ws;
    float*          Mf  = (float*)(ws + OFF_MF);
    unsigned short* B2T = (unsigned short*)(ws + OFF_B2T);
    unsigned short* Ahp = (unsigned short*)(ws + OFF_AH);
    unsigned short* Alp = (unsigned short*)(ws + OFF_AL);
    float*          G3  = (float*)(ws + OFF_G3);
    float*          H1  = (float*)(ws + OFF_H1);
    float*          H2  = (float*)(ws + OFF_H2);

    k_mod<<<64, 256, 0, stream>>>(emb, modW, Mf);
    k_splitb<<<256, 256, 0, stream>>>(Wh + 131072, B2T);
    k_h1<<<256, 256, 0, stream>>>(W0, b0, Mf, H1);
    k_h2<<<256, 256, 0, stream>>>(H1, Wh, bh, Mf + 4096, H2);
    k_h3ab<<<1024, 256, 0, stream>>>(H2, Wh + 65536, bh + 256, Mf + 8192, Ahp, Alp);
    k_gemm<<<512, 512, 0, stream>>>(Ahp, Alp, B2T, bh + 512, G3);
    k_out<<<2048, 256, 0, stream>>>(coords, G3, Mf + 12288, Wl, bl, out, N,
                                    2048 * 256 / 16);
  } else {
    k_direct<<<N, 256, 0, stream>>>(coords, W0, b0, Wh, bh, emb, modW, Wl, bl, out);
  }
}